// Round 15
// baseline (16953.160 us; speedup 1.0000x reference)
//
#include <hip/hip_runtime.h>
#include <hip/hip_bf16.h>
#include <math.h>

// ---------------- problem constants ----------------
constexpr int NB  = 8;
constexpr int TT  = 4096;
constexpr int DD  = 256;
constexpr int CK  = 64;
constexpr int NCK = 64;
constexpr float ETA_SC = 1e-3f;
constexpr float EPSV   = 1e-6f;

constexpr size_t MSZ = (size_t)DD*DD;   // 65536

// ---------- fp32 region (element offsets into float* W) ----------
constexpr size_t OFF_W2  = 0;                               // [8][6][256*256]
constexpr size_t OFF_W1B = OFF_W2  + (size_t)NB*6*MSZ;      // [8][4][256*256]  (k,v,q,mem)
constexpr size_t OFF_W1S = OFF_W1B + (size_t)NB*4*MSZ;      // [8][2][256]
constexpr size_t OFF_WSK = OFF_W1S + (size_t)NB*2*DD;       // [8][2][256]
constexpr size_t OFF_SCK = OFF_WSK + (size_t)NB*2*DD;       // [8][64]
constexpr size_t OFF_SCQ = OFF_SCK + (size_t)NB*CK;         // [8][64]
constexpr size_t OFF_VSUM= OFF_SCQ + (size_t)NB*CK;         // [8][64]
constexpr size_t OFF_ETA = OFF_VSUM+ (size_t)NB*CK;         // [8][64]
constexpr size_t OFF_GS  = OFF_ETA + (size_t)NB*CK;         // [8][2][64]
constexpr size_t OFF_SALP= OFF_GS  + (size_t)NB*2*CK;       // [8][64] sigmoid(alpha)
constexpr size_t OFF_ABAR= OFF_SALP+ (size_t)NB*CK;         // [8]
constexpr size_t OFF_BARC= OFF_ABAR + NB;                   // [8] per-b barrier counters (uint)
constexpr size_t FTOT    = OFF_BARC + NB;

// ---------- bf16 region (element offsets into __hip_bfloat16* B) ----------
constexpr size_t BOFF_F  = 0;                               // [3][8][64][256]  F_k,F_v,F_q
constexpr size_t BOFF_H  = BOFF_F  + (size_t)3*NB*CK*DD;    // [8][6][64][256]  h=gelu(zu)
constexpr size_t BOFF_GB = BOFF_H  + (size_t)NB*6*CK*DD;    // [8][4][64][256]  g (big mems)
constexpr size_t BOFF_P  = BOFF_GB + (size_t)NB*4*CK*DD;    // [8][6][64][256]  P (eta-scaled)

__device__ __forceinline__ int bigIdx(int m){ return (m==5)?3:m; }

__device__ __forceinline__ float geluf(float z){
  return 0.5f*z*(1.0f + erff(z*0.70710678118654752440f));
}
__device__ __forceinline__ float dgeluf(float z){
  float cdf = 0.5f*(1.0f + erff(z*0.70710678118654752440f));
  float pdf = expf(-0.5f*z*z)*0.39894228040143267794f;
  return cdf + z*pdf;
}
__device__ __forceinline__ float bfu(unsigned short u){
  unsigned int v = ((unsigned int)u)<<16;
  return __uint_as_float(v);
}
__device__ __forceinline__ float wsum(float v){
  #pragma unroll
  for (int off=32; off>0; off>>=1) v += __shfl_xor(v, off, 64);
  return v;
}

// per-b barrier: 32 blocks, monotone counter (no reset). Release/acquire via
// device-scope fences (correctness does NOT depend on XCD placement).
// BOUNDED spin: residency failure -> diagnosable wrong answer, not a hang.
__device__ __forceinline__ void bbar(unsigned int* cnt, unsigned int target){
  __syncthreads();
  if (threadIdx.x == 0){
    __threadfence();                              // release our writes
    atomicAdd(cnt, 1u);                           // device-scope arrive
    unsigned int it = 0;
    while (__hip_atomic_load(cnt, __ATOMIC_RELAXED, __HIP_MEMORY_SCOPE_AGENT) < target
           && ++it < (1u<<18))
      __builtin_amdgcn_s_sleep(2);
    __threadfence();                              // acquire others' writes
  }
  __syncthreads();
}

// GEMM with LOCKSTEP W-STREAMING (safe-barrier variant): the block's 4 waves
// read IDENTICAL W addresses (addr depends on cg=tid&63 only). A __syncthreads
// every 16 k (=16KB of W, half of L1) pins all 4 waves to the same L1 window
// so wave 1's L2 misses become waves 2-4's L1 hits. __syncthreads (vs raw
// s_barrier, r13 container-failure suspect) is proven across r4-r8; its
// implied waitcnt drain is ~satisfied at the barrier point (prior segment's
// loads already consumed by its FMAs).
// acc[rr][j] += sum_k A[rg*4+rr][k] * Wm[(cg+64j)*DD + k], A in LDS stride 260.
// FMA order identical to r7 -> identical numerics.
__device__ __forceinline__ void gfull(const float* __restrict__ sA,
      const float* __restrict__ Wm, int cg, int rg, float acc[4][4]){
  for (int seg=0; seg<16; seg++){
    __syncthreads();
    #pragma unroll
    for (int kq=0; kq<4; kq++){
      int kk = seg*16 + kq*4;
      float4 w0 = *(const float4*)(Wm + (size_t)(cg      )*DD + kk);
      float4 w1 = *(const float4*)(Wm + (size_t)(cg +  64)*DD + kk);
      float4 w2 = *(const float4*)(Wm + (size_t)(cg + 128)*DD + kk);
      float4 w3 = *(const float4*)(Wm + (size_t)(cg + 192)*DD + kk);
      #pragma unroll
      for (int rr=0; rr<4; rr++){
        float4 a = *(const float4*)(sA + (rg*4+rr)*260 + kk);
        acc[rr][0] += a.x*w0.x + a.y*w0.y + a.z*w0.z + a.w*w0.w;
        acc[rr][1] += a.x*w1.x + a.y*w1.y + a.z*w1.z + a.w*w1.w;
        acc[rr][2] += a.x*w2.x + a.y*w2.y + a.z*w2.z + a.w*w2.w;
        acc[rr][3] += a.x*w3.x + a.y*w3.y + a.z*w3.z + a.w*w3.w;
      }
    }
  }
}

// GEMM (non-transposed W), same lockstep structure:
// acc[rr][j] += sum_o A[rg*4+rr][o] * Wm[o*DD + cg+64j]
__device__ __forceinline__ void gfullT(const float* __restrict__ sA,
      const float* __restrict__ Wm, int cg, int rg, float acc[4][4]){
  for (int seg=0; seg<16; seg++){
    __syncthreads();
    #pragma unroll
    for (int kq=0; kq<4; kq++){
      int kk = seg*16 + kq*4;
      float wv[4][4];
      #pragma unroll
      for (int s=0;s<4;s++)
        #pragma unroll
        for (int j=0;j<4;j++)
          wv[s][j] = Wm[(size_t)(kk+s)*DD + cg+64*j];
      #pragma unroll
      for (int rr=0;rr<4;rr++){
        float4 a = *(const float4*)(sA + (rg*4+rr)*260 + kk);
        #pragma unroll
        for (int j=0;j<4;j++)
          acc[rr][j] += a.x*wv[0][j] + a.y*wv[1][j] + a.z*wv[2][j] + a.w*wv[3][j];
      }
    }
  }
}

// ---------------- init ----------------
__global__ __launch_bounds__(256) void initk(float* __restrict__ W,
  const float* kw1, const float* kw2, const float* vw1, const float* vw2,
  const float* qw1, const float* qw2, const float* ew1, const float* ew2,
  const float* ewsk, const float* aw1, const float* aw2, const float* awsk,
  const float* mw1, const float* mw2)
{
  int b = blockIdx.x/6, m = blockIdx.x%6;
  const float *w1s=nullptr,*w2s=nullptr,*wsks=nullptr;
  switch(m){
    case 0: w1s=kw1; w2s=kw2; break;
    case 1: w1s=vw1; w2s=vw2; break;
    case 2: w1s=qw1; w2s=qw2; break;
    case 3: w1s=ew1; w2s=ew2; wsks=ewsk; break;
    case 4: w1s=aw1; w2s=aw2; wsks=awsk; break;
    default: w1s=mw1; w2s=mw2; break;
  }
  if (m==0 && threadIdx.x==0)
    ((unsigned int*)(W + OFF_BARC))[b] = 0u;     // reset per-b barrier counter
  float* w2d = W + OFF_W2 + ((size_t)b*6+m)*MSZ;
  for (size_t i=threadIdx.x; i<MSZ; i+=256) w2d[i] = w2s[i];
  if (m==3 || m==4){
    int sm = m-3;
    float* w1d = W + OFF_W1S + ((size_t)b*2+sm)*DD;
    float* wsd = W + OFF_WSK + ((size_t)b*2+sm)*DD;
    for (int i=threadIdx.x;i<DD;i+=256){ w1d[i]=w1s[i]; wsd[i]=wsks[i]; }
  } else {
    float* w1d = W + OFF_W1B + ((size_t)b*4+bigIdx(m))*MSZ;
    for (size_t i=threadIdx.x;i<MSZ;i+=256) w1d[i] = w1s[i];
  }
}

// ---------------- persistent kernel: 8 per-b pipelines, XCD-local ----------------
// grid = 256 blocks; b = blk&7 -> with round-robin wg->XCD dispatch, the 32
// blocks of batch b land on XCD b (per-b weights ~2.6MB < 4MB XCD-L2: resident;
// PROVEN r7: FETCH 6.7GB -> 40MB). Perf heuristic only; correctness rests on
// the device-scope fences in bbar (G16).
__global__ __launch_bounds__(256, 1) void pers(const float* __restrict__ x,
        float* __restrict__ W, __hip_bfloat16* __restrict__ B,
        float* __restrict__ out)
{
  const int blk = blockIdx.x, tid = threadIdx.x;
  const int b = blk & 7, wb = blk >> 3;
  const int cg = tid & 63, rg = tid >> 6;
  unsigned int* cnt = ((unsigned int*)(W + OFF_BARC)) + b;
  unsigned int bar = 0;
  __shared__ __align__(16) float sMem[2*16*260];   // sX | sY (phase3 reuses as sT)
  __shared__ float sSc[64];
  __shared__ float sEt[64], sSk[64];
  float* sX = sMem;
  float* sY = sMem + 16*260;

  for (int ck=0; ck<NCK; ck++){
    // ================= phase 1: forward heads + row stats (20 tasks/b) =========
    for (int task=wb; task<20; task+=32){
      int m = task>>2, t0 = (task&3)*16;
      const float* xp = x + ((size_t)b*TT + (size_t)ck*CK + t0)*DD;
      for (int l=tid; l<1024; l+=256){
        int tl = l>>6, ii = (l&63)<<2;
        *(float4*)(sX + tl*260 + ii) = *(const float4*)(xp + (size_t)tl*DD + ii);
      }
      __syncthreads();
      const float* w2 = W + OFF_W2 + ((size_t)b*6+m)*MSZ;
      float acc1[4][4];
      #pragma unroll
      for (int i=0;i<4;i++){ acc1[i][0]=acc1[i][1]=acc1[i][2]=acc1[i][3]=0.0f; }
      gfull(sX, w2, cg, rg, acc1);
      if (m < 3){
        #pragma unroll
        for (int rr=0;rr<4;rr++)
          #pragma unroll
          for (int j=0;j<4;j++)
            sY[(rg*4+rr)*260 + cg+64*j] = geluf(acc1[rr][j]);
        __syncthreads();
        const float* w1 = W + OFF_W1B + ((size_t)b*4+m)*MSZ;
        float acc2[4][4];
        #pragma unroll
        for (int i=0;i<4;i++){ acc2[i][0]=acc2[i][1]=acc2[i][2]=acc2[i][3]=0.0f; }
        gfull(sY, w1, cg, rg, acc2);
        __hip_bfloat16* fd = B + BOFF_F + ((size_t)m*NB + b)*CK*DD;
        float p[4];
        #pragma unroll
        for (int rr=0;rr<4;rr++){
          float ps = 0.0f;
          #pragma unroll
          for (int j=0;j<4;j++){
            int col = cg+64*j;
            float F = sX[(rg*4+rr)*260 + col] + acc2[rr][j];
            fd[(size_t)(t0+rg*4+rr)*DD + col] = __float2bfloat16(F);
            ps += (m==1) ? F : F*F;
          }
          p[rr] = ps;
        }
        #pragma unroll
        for (int rr=0;rr<4;rr++){
          float v = wsum(p[rr]);
          if (cg == 0){
            int t = t0 + rg*4 + rr;
            if (m==0)      W[OFF_SCK + (size_t)b*CK + t] = 1.0f/fmaxf(sqrtf(v), EPSV);
            else if (m==2) W[OFF_SCQ + (size_t)b*CK + t] = 1.0f/fmaxf(sqrtf(v), EPSV);
            else           W[OFF_VSUM+ (size_t)b*CK + t] = v;
          }
        }
      } else {
        int sm = m-3;
        const float* w1s = W + OFF_W1S + ((size_t)b*2+sm)*DD;
        const float* wsk = W + OFF_WSK + ((size_t)b*2+sm)*DD;
        float p[4];
        #pragma unroll
        for (int rr=0;rr<4;rr++){
          float ps = 0.0f;
          #pragma unroll
          for (int j=0;j<4;j++){
            int col = cg+64*j;
            ps += sX[(rg*4+rr)*260+col]*wsk[col] + geluf(acc1[rr][j])*w1s[col];
          }
          p[rr] = ps;
        }
        #pragma unroll
        for (int rr=0;rr<4;rr++){
          float v = wsum(p[rr]);
          if (cg == 0){
            int t = t0 + rg*4 + rr;
            if (sm==0){
              float sp = (v>0.0f) ? (v + log1pf(expf(-v))) : log1pf(expf(v));
              W[OFF_ETA + (size_t)b*CK + t] = sp*ETA_SC;
            } else {
              W[OFF_SALP + (size_t)b*CK + t] = 1.0f/(1.0f+expf(-v));
            }
          }
        }
      }
      __syncthreads();
    }
    bar += 32; bbar(cnt, bar);

    // ================= phase 2: update-forward chains + output (29 tasks/b) ====
    for (int task=wb; task<29; task+=32){
      if (task < 28){
        int chn = task>>2, t0 = (task&3)*16;
        bool isq = (chn==6);
        const unsigned short* fsrc = (const unsigned short*)
            (B + BOFF_F + ((size_t)(isq?2:0)*NB + b)*CK*DD + (size_t)t0*DD);
        const float* scp = W + (isq?OFF_SCQ:OFF_SCK) + (size_t)b*CK + t0;
        if (tid < 16)       sSc[tid] = scp[tid];
        else if (tid < 32)  sSc[tid] = W[OFF_ETA + (size_t)b*CK + t0 + (tid-16)];
        else if (tid < 48)  sSc[tid] = W[OFF_VSUM+ (size_t)b*CK + t0 + (tid-32)];
        __syncthreads();
        for (int l=tid; l<1024; l+=256){
          int tl = l>>6, ii = (l&63)<<2;
          ushort4 u = *(const ushort4*)(fsrc + (size_t)tl*DD + ii);
          float s = sSc[tl];
          float4 t4;
          t4.x = bfu(u.x)*s; t4.y = bfu(u.y)*s; t4.z = bfu(u.z)*s; t4.w = bfu(u.w)*s;
          *(float4*)(sX + tl*260 + ii) = t4;
        }
        __syncthreads();
        int m2 = isq ? 5 : chn;
        const float* w2 = W + OFF_W2 + ((size_t)b*6+m2)*MSZ;
        float acc1[4][4];
        #pragma unroll
        for (int i=0;i<4;i++){ acc1[i][0]=acc1[i][1]=acc1[i][2]=acc1[i][3]=0.0f; }
        gfull(sX, w2, cg, rg, acc1);   // zu (or zo)

        if (chn==0 || chn==1 || chn==2 || chn==5){
          int mi = (chn==5)?3:chn;
          __hip_bfloat16* hd = B + BOFF_H + ((size_t)(b*6+chn))*CK*DD;
          #pragma unroll
          for (int rr=0;rr<4;rr++)
            #pragma unroll
            for (int j=0;j<4;j++){
              float h = geluf(acc1[rr][j]);
              sY[(rg*4+rr)*260 + cg+64*j] = h;
              hd[(size_t)(t0+rg*4+rr)*DD + cg+64*j] = __float2bfloat16(h);
            }
          __syncthreads();
          const float* w1 = W + OFF_W1B + ((size_t)b*4+mi)*MSZ;
          float acc2[4][4];
          #pragma unroll
          for (int i=0;i<4;i++){ acc2[i][0]=acc2[i][1]=acc2[i][2]=acc2[i][3]=0.0f; }
          gfull(sY, w1, cg, rg, acc2);
          __syncthreads();   // all waves done reading sY(h) before overwrite with g
          const unsigned short* fv = (const unsigned short*)
              (B + BOFF_F + ((size_t)1*NB + b)*CK*DD + (size_t)t0*DD);
          __hip_bfloat16* gd = B + BOFF_GB + ((size_t)(b*4+mi))*CK*DD;
          #pragma unroll
          for (int rr=0;rr<4;rr++)
            #pragma unroll
            for (int j=0;j<4;j++){
              int col = cg+64*j;
              float g = 2.0f*( sX[(rg*4+rr)*260+col] + acc2[rr][j]
                               - bfu(fv[(size_t)(rg*4+rr)*DD+col]) );
              sY[(rg*4+rr)*260+col] = g;
              gd[(size_t)(t0+rg*4+rr)*DD + col] = __float2bfloat16(g);
            }
          __syncthreads();
          float accp[4][4];
          #pragma unroll
          for (int i=0;i<4;i++){ accp[i][0]=accp[i][1]=accp[i][2]=accp[i][3]=0.0f; }
          gfullT(sY, w1, cg, rg, accp);   // pre = g @ w1
          __hip_bfloat16* pd2 = B + BOFF_P + ((size_t)(b*6+chn))*CK*DD;
          #pragma unroll
          for (int rr=0;rr<4;rr++){
            float et = sSc[16 + rg*4+rr];
            #pragma unroll
            for (int j=0;j<4;j++)
              pd2[(size_t)(t0+rg*4+rr)*DD + cg+64*j] =
                __float2bfloat16(accp[rr][j]*dgeluf(acc1[rr][j])*et);
          }
        } else if (chn==6){
          #pragma unroll
          for (int rr=0;rr<4;rr++)
            #pragma unroll
            for (int j=0;j<4;j++)
              sY[(rg*4+rr)*260 + cg+64*j] = geluf(acc1[rr][j]);
          __syncthreads();
          const float* w1 = W + OFF_W1B + ((size_t)b*4+3)*MSZ;
          float acc2[4][4];
          #pragma unroll
          for (int i=0;i<4;i++){ acc2[i][0]=acc2[i][1]=acc2[i][2]=acc2[i][3]=0.0f; }
          gfull(sY, w1, cg, rg, acc2);
          float* op = out + ((size_t)b*TT + (size_t)ck*CK + t0)*DD;
          #pragma unroll
          for (int rr=0;rr<4;rr++)
            #pragma unroll
            for (int j=0;j<4;j++){
              int col = cg+64*j;
              op[(size_t)(rg*4+rr)*DD + col] = sX[(rg*4+rr)*260+col] + acc2[rr][j];
            }
        } else {
          int sm = chn-3;
          __hip_bfloat16* hd = B + BOFF_H + ((size_t)(b*6+chn))*CK*DD;
          const float* w1s = W + OFF_W1S + ((size_t)b*2+sm)*DD;
          const float* wsk = W + OFF_WSK + ((size_t)b*2+sm)*DD;
          float p[4];
          #pragma unroll
          for (int rr=0;rr<4;rr++){
            float ps = 0.0f;
            #pragma unroll
            for (int j=0;j<4;j++){
              int col = cg+64*j;
              float h = geluf(acc1[rr][j]);
              hd[(size_t)(t0+rg*4+rr)*DD + col] = __float2bfloat16(h);
              ps += sX[(rg*4+rr)*260+col]*wsk[col] + h*w1s[col];
            }
            p[rr] = ps;
          }
          __hip_bfloat16* pd2 = B + BOFF_P + ((size_t)(b*6+chn))*CK*DD;
          #pragma unroll
          for (int rr=0;rr<4;rr++){
            float f = wsum(p[rr]);                      // all lanes hold row value
            int t = t0 + rg*4 + rr;
            float gs = 2.0f*(256.0f*f - sSc[32 + rg*4+rr]);
            if (cg == 0) W[OFF_GS + ((size_t)b*2+sm)*CK + t] = gs;
            float ge = gs * sSc[16 + rg*4+rr];          // g*eta
            #pragma unroll
            for (int j=0;j<4;j++){
              int col = cg+64*j;
              pd2[(size_t)t*DD + col] =
                __float2bfloat16(ge*w1s[col]*dgeluf(acc1[rr][j]));
            }
          }
        }
      } else {
        // abar = prod_t sigmoid(alpha_t)
        if (tid < 64){
          float v = W[OFF_SALP + (size_t)b*CK + tid];
          #pragma unroll
          for (int off=32; off>0; off>>=1) v *= __shfl_xor(v, off, 64);
          if (tid == 0) W[OFF_ABAR + b] = v;
        }
      }
      __syncthreads();
    }
    bar += 32; bbar(cnt, bar);

    // ================= phase 3: state updates (82 half-tasks/b) ================
    {
      if (tid < 64){
        sEt[tid] = W[OFF_ETA + (size_t)b*CK + tid];
        sSk[tid] = W[OFF_SCK + (size_t)b*CK + tid];
      }
      __syncthreads();
      float ab = W[OFF_ABAR + b];
      const unsigned short* fk = (const unsigned short*)(B + BOFF_F + ((size_t)0*NB+b)*CK*DD);
      float* sT = sMem;      // 32*68 floats used
      int c = tid;
      for (int task=wb; task<82; task+=32){
        if (task < 32){
          // w1[o0..o0+31][c] -= sum_t g[t,o]*eta[t]*h[t,c]
          int mi = task>>3, o0 = (task&7)*32;
          int m = (mi==3)?5:mi;
          const unsigned short* hb = (const unsigned short*)(B + BOFF_H + ((size_t)(b*6+m))*CK*DD);
          const unsigned short* gb = (const unsigned short*)(B + BOFF_GB + ((size_t)(b*4+mi))*CK*DD);
          float* w1 = W + OFF_W1B + ((size_t)b*4+mi)*MSZ;
          float hv[64];
          #pragma unroll
          for (int t=0;t<64;t++) hv[t] = bfu(hb[(size_t)t*DD + c]);
          for (int l=tid; l<2048; l+=256){
            int t=l>>5, oo=l&31;
            sT[oo*68+t] = bfu(gb[(size_t)t*DD + o0+oo]) * sEt[t];
          }
          __syncthreads();
          for (int oo=0; oo<32; oo++){
            float s = 0.0f;
            #pragma unroll
            for (int t4=0; t4<16; t4++){
              float4 g4 = *(const float4*)(sT + oo*68 + t4*4);
              s += g4.x*hv[4*t4] + g4.y*hv[4*t4+1] + g4.z*hv[4*t4+2] + g4.w*hv[4*t4+3];
            }
            size_t idx = (size_t)(o0+oo)*DD + c;
            w1[idx] = ab*w1[idx] - s;
          }
        } else if (task < 80){
          // w2[h0..h0+31][c] -= sum_t P[t,h]*k[t,c]
          int r = task-32, m = r>>3, h0 = (r&7)*32;
          const unsigned short* pd2 = (const unsigned short*)(B + BOFF_P + ((size_t)(b*6+m))*CK*DD);
          float* w2 = W + OFF_W2 + ((size_t)b*6+m)*MSZ;
          float kc[64];
          #pragma unroll
          for (int t=0;t<64;t++) kc[t] = bfu(fk[(size_t)t*DD+c]) * sSk[t];
          for (int l=tid; l<2048; l+=256){
            int t=l>>5, hh=l&31;
            sT[hh*68+t] = bfu(pd2[(size_t)t*DD + h0+hh]);
          }
          __syncthreads();
          for (int hh=0; hh<32; hh++){
            float s = 0.0f;
            #pragma unroll
            for (int t4=0; t4<16; t4++){
              float4 p4 = *(const float4*)(sT + hh*68 + t4*4);
              s += p4.x*kc[4*t4] + p4.y*kc[4*t4+1] + p4.z*kc[4*t4+2] + p4.w*kc[4*t4+3];
            }
            size_t idx = (size_t)(h0+hh)*DD + c;
            w2[idx] = ab*w2[idx] - s;
          }
        } else {
          // small-state updates
          int sm = task-80, m = 3+sm;
          const unsigned short* hb = (const unsigned short*)(B + BOFF_H + ((size_t)(b*6+m))*CK*DD);
          float s1=0.0f, s2=0.0f;
          #pragma unroll
          for (int t=0;t<64;t++){
            float ge = W[OFF_GS + ((size_t)b*2+sm)*CK + t] * sEt[t];
            s1 += ge * bfu(hb[(size_t)t*DD+c]);
            s2 += ge * bfu(fk[(size_t)t*DD+c]) * sSk[t];
          }
          float* w1s = W + OFF_W1S + ((size_t)b*2+sm)*DD;
          float* wskp= W + OFF_WSK + ((size_t)b*2+sm)*DD;
          w1s[c]  = ab*w1s[c]  - s1;
          wskp[c] = ab*wskp[c] - s2;
        }
        __syncthreads();
      }
    }
    bar += 32; bbar(cnt, bar);
  }
}

// ---------------- host ----------------
extern "C" void kernel_launch(void* const* d_in, const int* in_sizes, int n_in,
                              void* d_out, int out_size, void* d_ws, size_t ws_size,
                              hipStream_t stream){
  const float* x = (const float*)d_in[0];
  float* W = (float*)d_ws;
  __hip_bfloat16* B = (__hip_bfloat16*)(W + FTOT);
  float* out = (float*)d_out;

  initk<<<NB*6, 256, 0, stream>>>(W,
      (const float*)d_in[1], (const float*)d_in[2],
      (const float*)d_in[3], (const float*)d_in[4],
      (const float*)d_in[5], (const float*)d_in[6],
      (const float*)d_in[7], (const float*)d_in[8],
      (const float*)d_in[9], (const float*)d_in[10],
      (const float*)d_in[11], (const float*)d_in[12],
      (const float*)d_in[13], (const float*)d_in[14]);

  pers<<<256, 256, 0, stream>>>(x, W, B, out);
}

// Round 16
// 13257.895 us; speedup vs baseline: 1.2787x; 1.2787x over previous
//
#include <hip/hip_runtime.h>
#include <hip/hip_bf16.h>
#include <math.h>

// ---------------- problem constants ----------------
constexpr int NB  = 8;
constexpr int TT  = 4096;
constexpr int DD  = 256;
constexpr int CK  = 64;
constexpr int NCK = 64;
constexpr float ETA_SC = 1e-3f;
constexpr float EPSV   = 1e-6f;

constexpr size_t MSZ = (size_t)DD*DD;   // 65536

// ---------- fp32 region (element offsets into float* W) ----------
// All big matrices stored REDUCTION-MAJOR so GEMM reads are coalesced b128:
//   W2T[i][h] (forward z=x*W2^T reduces over i)
//   W1T[h][o] (forward F=h*W1^T reduces over h)
//   W1N[o][h] (pre=g*W1 reduces over o) -- second copy of W1
constexpr size_t OFF_W2T = 0;                               // [8][6][256*256]
constexpr size_t OFF_W1T = OFF_W2T + (size_t)NB*6*MSZ;      // [8][4][256*256]
constexpr size_t OFF_W1N = OFF_W1T + (size_t)NB*4*MSZ;      // [8][4][256*256]
constexpr size_t OFF_W1S = OFF_W1N + (size_t)NB*4*MSZ;      // [8][2][256]
constexpr size_t OFF_WSK = OFF_W1S + (size_t)NB*2*DD;       // [8][2][256]
constexpr size_t OFF_SCK = OFF_WSK + (size_t)NB*2*DD;       // [8][64]
constexpr size_t OFF_SCQ = OFF_SCK + (size_t)NB*CK;         // [8][64]
constexpr size_t OFF_VSUM= OFF_SCQ + (size_t)NB*CK;         // [8][64]
constexpr size_t OFF_ETA = OFF_VSUM+ (size_t)NB*CK;         // [8][64]
constexpr size_t OFF_GS  = OFF_ETA + (size_t)NB*CK;         // [8][2][64]
constexpr size_t OFF_SALP= OFF_GS  + (size_t)NB*2*CK;       // [8][64]
constexpr size_t OFF_ABAR= OFF_SALP+ (size_t)NB*CK;         // [8]
constexpr size_t OFF_BARC= OFF_ABAR + NB;                   // [8] barrier counters
constexpr size_t FTOT    = OFF_BARC + NB;

// ---------- bf16 region (ushort element offsets) ----------
constexpr size_t BOFF_F  = 0;                               // [3][8][64][256]
constexpr size_t BOFF_H  = BOFF_F  + (size_t)3*NB*CK*DD;    // [8][6][64][256]
constexpr size_t BOFF_GB = BOFF_H  + (size_t)NB*6*CK*DD;    // [8][4][64][256]
constexpr size_t BOFF_P  = BOFF_GB + (size_t)NB*4*CK*DD;    // [8][6][64][256]

__device__ __forceinline__ int bigIdx(int m){ return (m==5)?3:m; }

__device__ __forceinline__ float geluf(float z){
  return 0.5f*z*(1.0f + erff(z*0.70710678118654752440f));
}
__device__ __forceinline__ float dgeluf(float z){
  float cdf = 0.5f*(1.0f + erff(z*0.70710678118654752440f));
  float pdf = expf(-0.5f*z*z)*0.39894228040143267794f;
  return cdf + z*pdf;
}
__device__ __forceinline__ float bfu(unsigned short u){
  unsigned int v = ((unsigned int)u)<<16;
  return __uint_as_float(v);
}
__device__ __forceinline__ unsigned short f2bu(float f){
  __hip_bfloat16 h = __float2bfloat16(f);
  union { __hip_bfloat16 b; unsigned short u; } cv; cv.b = h; return cv.u;
}
__device__ __forceinline__ float wsum(float v){
  #pragma unroll
  for (int off=32; off>0; off>>=1) v += __shfl_xor(v, off, 64);
  return v;
}

// per-b barrier (proven r4-r8): monotone counter, device-scope fences,
// bounded spin (residency failure -> wrong answer, not a hang).
__device__ __forceinline__ void bbar(unsigned int* cnt, unsigned int target){
  __syncthreads();
  if (threadIdx.x == 0){
    __threadfence();
    atomicAdd(cnt, 1u);
    unsigned int it = 0;
    while (__hip_atomic_load(cnt, __ATOMIC_RELAXED, __HIP_MEMORY_SCOPE_AGENT) < target
           && ++it < (1u<<18))
      __builtin_amdgcn_s_sleep(2);
    __threadfence();
  }
  __syncthreads();
}

// COALESCED GEMM: lane cg owns output cols 4cg..4cg+3.
// acc[rr][j] += sum_k A[rg*4+rr][k] * Mt[k*DD + 4cg+j]  (Mt reduction-major)
// W operand: one float4 per k, 64 lanes x 16B CONTIGUOUS -> fully coalesced
// (vs r7's 64-lines-per-instruction stride-1KB pattern). Per-element
// reduction order identical to r7 -> same numerics.
__device__ __forceinline__ void gcoal(const float* __restrict__ sA,
      const float* __restrict__ Mt, int cg, int rg, float acc[4][4]){
  const float* mp = Mt + 4*cg;
  #pragma unroll 4
  for (int kk=0; kk<256; kk+=4){
    float4 w0 = *(const float4*)(mp + (size_t)(kk  )*DD);
    float4 w1 = *(const float4*)(mp + (size_t)(kk+1)*DD);
    float4 w2 = *(const float4*)(mp + (size_t)(kk+2)*DD);
    float4 w3 = *(const float4*)(mp + (size_t)(kk+3)*DD);
    #pragma unroll
    for (int rr=0; rr<4; rr++){
      float4 a = *(const float4*)(sA + (rg*4+rr)*260 + kk);
      acc[rr][0] += a.x*w0.x + a.y*w1.x + a.z*w2.x + a.w*w3.x;
      acc[rr][1] += a.x*w0.y + a.y*w1.y + a.z*w2.y + a.w*w3.y;
      acc[rr][2] += a.x*w0.z + a.y*w1.z + a.z*w2.z + a.w*w3.z;
      acc[rr][3] += a.x*w0.w + a.y*w1.w + a.z*w2.w + a.w*w3.w;
    }
  }
}

// ---------------- init: build transposed weight copies ----------------
__global__ __launch_bounds__(256) void initk(float* __restrict__ W,
  const float* kw1, const float* kw2, const float* vw1, const float* vw2,
  const float* qw1, const float* qw2, const float* ew1, const float* ew2,
  const float* ewsk, const float* aw1, const float* aw2, const float* awsk,
  const float* mw1, const float* mw2)
{
  int b = blockIdx.x/6, m = blockIdx.x%6;
  const float *w1src=nullptr,*w2src=nullptr,*wsks=nullptr;
  switch(m){
    case 0: w1src=kw1; w2src=kw2; break;
    case 1: w1src=vw1; w2src=vw2; break;
    case 2: w1src=qw1; w2src=qw2; break;
    case 3: w1src=ew1; w2src=ew2; wsks=ewsk; break;
    case 4: w1src=aw1; w2src=aw2; wsks=awsk; break;
    default: w1src=mw1; w2src=mw2; break;
  }
  if (m==0 && threadIdx.x==0)
    ((unsigned int*)(W + OFF_BARC))[b] = 0u;
  // W2T[i][h] = w2src[h][i]
  float* w2t = W + OFF_W2T + ((size_t)b*6+m)*MSZ;
  for (size_t l=threadIdx.x; l<MSZ; l+=256){
    size_t i = l>>8, h = l&255;
    w2t[l] = w2src[h*(size_t)DD + i];
  }
  if (m==3 || m==4){
    int sm = m-3;
    float* w1d = W + OFF_W1S + ((size_t)b*2+sm)*DD;
    float* wsd = W + OFF_WSK + ((size_t)b*2+sm)*DD;
    for (int i=threadIdx.x;i<DD;i+=256){ w1d[i]=w1src[i]; wsd[i]=wsks[i]; }
  } else {
    int mi = bigIdx(m);
    float* w1t = W + OFF_W1T + ((size_t)b*4+mi)*MSZ;   // [h][o]
    float* w1n = W + OFF_W1N + ((size_t)b*4+mi)*MSZ;   // [o][h]
    for (size_t l=threadIdx.x; l<MSZ; l+=256){
      size_t h = l>>8, o = l&255;
      w1t[l] = w1src[o*(size_t)DD + h];
      w1n[l] = w1src[l];
    }
  }
}

// ---------------- persistent kernel: 8 per-b pipelines, XCD-local ----------------
// grid 256; b=blk&7 (weights XCD-L2-resident, PROVEN r7: FETCH 6.7GB->40MB).
__global__ __launch_bounds__(256, 1) void pers(const float* __restrict__ x,
        float* __restrict__ W, __hip_bfloat16* __restrict__ Bb,
        float* __restrict__ out)
{
  unsigned short* B = (unsigned short*)Bb;
  const int blk = blockIdx.x, tid = threadIdx.x;
  const int b = blk & 7, wb = blk >> 3;
  const int cg = tid & 63, rg = tid >> 6;
  unsigned int* cnt = ((unsigned int*)(W + OFF_BARC)) + b;
  unsigned int bar = 0;
  __shared__ __align__(16) float sMem[2*16*260];
  __shared__ float sSc[64];
  __shared__ float sEt[64], sSk[64];
  float* sX = sMem;
  float* sY = sMem + 16*260;

  for (int ck=0; ck<NCK; ck++){
    // ===== phase 1: forward heads + row stats (20 tasks/b) =====
    for (int task=wb; task<20; task+=32){
      int m = task>>2, t0 = (task&3)*16;
      const float* xp = x + ((size_t)b*TT + (size_t)ck*CK + t0)*DD;
      for (int l=tid; l<1024; l+=256){
        int tl = l>>6, ii = (l&63)<<2;
        *(float4*)(sX + tl*260 + ii) = *(const float4*)(xp + (size_t)tl*DD + ii);
      }
      __syncthreads();
      float acc1[4][4];
      #pragma unroll
      for (int i=0;i<4;i++){ acc1[i][0]=acc1[i][1]=acc1[i][2]=acc1[i][3]=0.0f; }
      gcoal(sX, W + OFF_W2T + ((size_t)b*6+m)*MSZ, cg, rg, acc1);
      if (m < 3){
        #pragma unroll
        for (int rr=0;rr<4;rr++){
          float4 h4;
          h4.x=geluf(acc1[rr][0]); h4.y=geluf(acc1[rr][1]);
          h4.z=geluf(acc1[rr][2]); h4.w=geluf(acc1[rr][3]);
          *(float4*)(sY + (rg*4+rr)*260 + 4*cg) = h4;
        }
        __syncthreads();
        float acc2[4][4];
        #pragma unroll
        for (int i=0;i<4;i++){ acc2[i][0]=acc2[i][1]=acc2[i][2]=acc2[i][3]=0.0f; }
        gcoal(sY, W + OFF_W1T + ((size_t)b*4+m)*MSZ, cg, rg, acc2);
        unsigned short* fd = B + BOFF_F + ((size_t)m*NB + b)*CK*DD;
        float p[4];
        #pragma unroll
        for (int rr=0;rr<4;rr++){
          float4 xv = *(const float4*)(sX + (rg*4+rr)*260 + 4*cg);
          float F0=xv.x+acc2[rr][0], F1=xv.y+acc2[rr][1];
          float F2=xv.z+acc2[rr][2], F3=xv.w+acc2[rr][3];
          ushort4 u; u.x=f2bu(F0); u.y=f2bu(F1); u.z=f2bu(F2); u.w=f2bu(F3);
          *(ushort4*)(fd + (size_t)(t0+rg*4+rr)*DD + 4*cg) = u;
          p[rr] = (m==1) ? (F0+F1+F2+F3) : (F0*F0+F1*F1+F2*F2+F3*F3);
        }
        #pragma unroll
        for (int rr=0;rr<4;rr++){
          float v = wsum(p[rr]);
          if (cg == 0){
            int t = t0 + rg*4 + rr;
            if (m==0)      W[OFF_SCK + (size_t)b*CK + t] = 1.0f/fmaxf(sqrtf(v), EPSV);
            else if (m==2) W[OFF_SCQ + (size_t)b*CK + t] = 1.0f/fmaxf(sqrtf(v), EPSV);
            else           W[OFF_VSUM+ (size_t)b*CK + t] = v;
          }
        }
      } else {
        int sm = m-3;
        const float* w1s = W + OFF_W1S + ((size_t)b*2+sm)*DD;
        const float* wsk = W + OFF_WSK + ((size_t)b*2+sm)*DD;
        float4 w1v = *(const float4*)(w1s + 4*cg);
        float4 wkv = *(const float4*)(wsk + 4*cg);
        float p[4];
        #pragma unroll
        for (int rr=0;rr<4;rr++){
          float4 xv = *(const float4*)(sX + (rg*4+rr)*260 + 4*cg);
          p[rr] = xv.x*wkv.x + xv.y*wkv.y + xv.z*wkv.z + xv.w*wkv.w
                + geluf(acc1[rr][0])*w1v.x + geluf(acc1[rr][1])*w1v.y
                + geluf(acc1[rr][2])*w1v.z + geluf(acc1[rr][3])*w1v.w;
        }
        #pragma unroll
        for (int rr=0;rr<4;rr++){
          float v = wsum(p[rr]);
          if (cg == 0){
            int t = t0 + rg*4 + rr;
            if (sm==0){
              float sp = (v>0.0f) ? (v + log1pf(expf(-v))) : log1pf(expf(v));
              W[OFF_ETA + (size_t)b*CK + t] = sp*ETA_SC;
            } else {
              W[OFF_SALP + (size_t)b*CK + t] = 1.0f/(1.0f+expf(-v));
            }
          }
        }
      }
      __syncthreads();
    }
    bar += 32; bbar(cnt, bar);

    // ===== phase 2: update-forward chains + output (29 tasks/b) =====
    for (int task=wb; task<29; task+=32){
      if (task < 28){
        int chn = task>>2, t0 = (task&3)*16;
        bool isq = (chn==6);
        const unsigned short* fsrc = B + BOFF_F + ((size_t)(isq?2:0)*NB + b)*CK*DD
                                       + (size_t)t0*DD;
        const float* scp = W + (isq?OFF_SCQ:OFF_SCK) + (size_t)b*CK + t0;
        if (tid < 16)       sSc[tid] = scp[tid];
        else if (tid < 32)  sSc[tid] = W[OFF_ETA + (size_t)b*CK + t0 + (tid-16)];
        else if (tid < 48)  sSc[tid] = W[OFF_VSUM+ (size_t)b*CK + t0 + (tid-32)];
        __syncthreads();
        for (int l=tid; l<1024; l+=256){
          int tl = l>>6, ii = (l&63)<<2;
          ushort4 u = *(const ushort4*)(fsrc + (size_t)tl*DD + ii);
          float s = sSc[tl];
          float4 t4;
          t4.x = bfu(u.x)*s; t4.y = bfu(u.y)*s; t4.z = bfu(u.z)*s; t4.w = bfu(u.w)*s;
          *(float4*)(sX + tl*260 + ii) = t4;
        }
        __syncthreads();
        int m2 = isq ? 5 : chn;
        float acc1[4][4];
        #pragma unroll
        for (int i=0;i<4;i++){ acc1[i][0]=acc1[i][1]=acc1[i][2]=acc1[i][3]=0.0f; }
        gcoal(sX, W + OFF_W2T + ((size_t)b*6+m2)*MSZ, cg, rg, acc1);  // zu/zo

        if (chn==0 || chn==1 || chn==2 || chn==5){
          int mi = (chn==5)?3:chn;
          unsigned short* hd = B + BOFF_H + ((size_t)(b*6+chn))*CK*DD;
          #pragma unroll
          for (int rr=0;rr<4;rr++){
            float4 h4;
            h4.x=geluf(acc1[rr][0]); h4.y=geluf(acc1[rr][1]);
            h4.z=geluf(acc1[rr][2]); h4.w=geluf(acc1[rr][3]);
            *(float4*)(sY + (rg*4+rr)*260 + 4*cg) = h4;
            ushort4 hu; hu.x=f2bu(h4.x); hu.y=f2bu(h4.y); hu.z=f2bu(h4.z); hu.w=f2bu(h4.w);
            *(ushort4*)(hd + (size_t)(t0+rg*4+rr)*DD + 4*cg) = hu;
          }
          __syncthreads();
          float acc2[4][4];
          #pragma unroll
          for (int i=0;i<4;i++){ acc2[i][0]=acc2[i][1]=acc2[i][2]=acc2[i][3]=0.0f; }
          gcoal(sY, W + OFF_W1T + ((size_t)b*4+mi)*MSZ, cg, rg, acc2);
          __syncthreads();   // done reading sY(h) before overwrite with g
          const unsigned short* fvp = B + BOFF_F + ((size_t)1*NB + b)*CK*DD
                                        + (size_t)t0*DD;
          unsigned short* gd = B + BOFF_GB + ((size_t)(b*4+mi))*CK*DD;
          #pragma unroll
          for (int rr=0;rr<4;rr++){
            float4 xv = *(const float4*)(sX + (rg*4+rr)*260 + 4*cg);
            ushort4 fv4 = *(const ushort4*)(fvp + (size_t)(rg*4+rr)*DD + 4*cg);
            float4 g4;
            g4.x = 2.0f*(xv.x + acc2[rr][0] - bfu(fv4.x));
            g4.y = 2.0f*(xv.y + acc2[rr][1] - bfu(fv4.y));
            g4.z = 2.0f*(xv.z + acc2[rr][2] - bfu(fv4.z));
            g4.w = 2.0f*(xv.w + acc2[rr][3] - bfu(fv4.w));
            *(float4*)(sY + (rg*4+rr)*260 + 4*cg) = g4;
            ushort4 gu; gu.x=f2bu(g4.x); gu.y=f2bu(g4.y); gu.z=f2bu(g4.z); gu.w=f2bu(g4.w);
            *(ushort4*)(gd + (size_t)(t0+rg*4+rr)*DD + 4*cg) = gu;
          }
          __syncthreads();
          float accp[4][4];
          #pragma unroll
          for (int i=0;i<4;i++){ accp[i][0]=accp[i][1]=accp[i][2]=accp[i][3]=0.0f; }
          gcoal(sY, W + OFF_W1N + ((size_t)b*4+mi)*MSZ, cg, rg, accp);  // pre = g@w1
          unsigned short* pd2 = B + BOFF_P + ((size_t)(b*6+chn))*CK*DD;
          #pragma unroll
          for (int rr=0;rr<4;rr++){
            float et = sSc[16 + rg*4+rr];
            ushort4 pu;
            pu.x = f2bu(accp[rr][0]*dgeluf(acc1[rr][0])*et);
            pu.y = f2bu(accp[rr][1]*dgeluf(acc1[rr][1])*et);
            pu.z = f2bu(accp[rr][2]*dgeluf(acc1[rr][2])*et);
            pu.w = f2bu(accp[rr][3]*dgeluf(acc1[rr][3])*et);
            *(ushort4*)(pd2 + (size_t)(t0+rg*4+rr)*DD + 4*cg) = pu;
          }
        } else if (chn==6){
          #pragma unroll
          for (int rr=0;rr<4;rr++){
            float4 h4;
            h4.x=geluf(acc1[rr][0]); h4.y=geluf(acc1[rr][1]);
            h4.z=geluf(acc1[rr][2]); h4.w=geluf(acc1[rr][3]);
            *(float4*)(sY + (rg*4+rr)*260 + 4*cg) = h4;
          }
          __syncthreads();
          float acc2[4][4];
          #pragma unroll
          for (int i=0;i<4;i++){ acc2[i][0]=acc2[i][1]=acc2[i][2]=acc2[i][3]=0.0f; }
          gcoal(sY, W + OFF_W1T + ((size_t)b*4+3)*MSZ, cg, rg, acc2);
          float* op = out + ((size_t)b*TT + (size_t)ck*CK + t0)*DD;
          #pragma unroll
          for (int rr=0;rr<4;rr++){
            float4 xv = *(const float4*)(sX + (rg*4+rr)*260 + 4*cg);
            float4 o4;
            o4.x = xv.x + acc2[rr][0]; o4.y = xv.y + acc2[rr][1];
            o4.z = xv.z + acc2[rr][2]; o4.w = xv.w + acc2[rr][3];
            *(float4*)(op + (size_t)(rg*4+rr)*DD + 4*cg) = o4;
          }
        } else {
          int sm = chn-3;
          unsigned short* hd = B + BOFF_H + ((size_t)(b*6+chn))*CK*DD;
          const float* w1s = W + OFF_W1S + ((size_t)b*2+sm)*DD;
          const float* wsk = W + OFF_WSK + ((size_t)b*2+sm)*DD;
          float4 w1v = *(const float4*)(w1s + 4*cg);
          float4 wkv = *(const float4*)(wsk + 4*cg);
          float p[4];
          #pragma unroll
          for (int rr=0;rr<4;rr++){
            float4 xv = *(const float4*)(sX + (rg*4+rr)*260 + 4*cg);
            float h0=geluf(acc1[rr][0]), h1=geluf(acc1[rr][1]);
            float h2=geluf(acc1[rr][2]), h3=geluf(acc1[rr][3]);
            ushort4 hu; hu.x=f2bu(h0); hu.y=f2bu(h1); hu.z=f2bu(h2); hu.w=f2bu(h3);
            *(ushort4*)(hd + (size_t)(t0+rg*4+rr)*DD + 4*cg) = hu;
            p[rr] = xv.x*wkv.x + xv.y*wkv.y + xv.z*wkv.z + xv.w*wkv.w
                  + h0*w1v.x + h1*w1v.y + h2*w1v.z + h3*w1v.w;
          }
          unsigned short* pd2 = B + BOFF_P + ((size_t)(b*6+chn))*CK*DD;
          #pragma unroll
          for (int rr=0;rr<4;rr++){
            float f = wsum(p[rr]);
            int t = t0 + rg*4 + rr;
            float gs = 2.0f*(256.0f*f - sSc[32 + rg*4+rr]);
            if (cg == 0) W[OFF_GS + ((size_t)b*2+sm)*CK + t] = gs;
            float ge = gs * sSc[16 + rg*4+rr];
            ushort4 pu;
            pu.x = f2bu(ge*w1v.x*dgeluf(acc1[rr][0]));
            pu.y = f2bu(ge*w1v.y*dgeluf(acc1[rr][1]));
            pu.z = f2bu(ge*w1v.z*dgeluf(acc1[rr][2]));
            pu.w = f2bu(ge*w1v.w*dgeluf(acc1[rr][3]));
            *(ushort4*)(pd2 + (size_t)t*DD + 4*cg) = pu;
          }
        }
      } else {
        // abar = prod_t sigmoid(alpha_t)
        if (tid < 64){
          float v = W[OFF_SALP + (size_t)b*CK + tid];
          #pragma unroll
          for (int off=32; off>0; off>>=1) v *= __shfl_xor(v, off, 64);
          if (tid == 0) W[OFF_ABAR + b] = v;
        }
      }
      __syncthreads();
    }
    bar += 32; bbar(cnt, bar);

    // ===== phase 3: state updates (58 tasks/b, 64-wide segments) =====
    {
      if (tid < 64){
        sEt[tid] = W[OFF_ETA + (size_t)b*CK + tid];
        sSk[tid] = W[OFF_SCK + (size_t)b*CK + tid];
      }
      __syncthreads();
      float ab = W[OFF_ABAR + b];
      const unsigned short* fk = B + BOFF_F + ((size_t)0*NB+b)*CK*DD;
      float* sT = sMem;      // 64*68 floats
      int c = tid;
      for (int task=wb; task<58; task+=32){
        if (task < 16){
          // W1N[o][h] -= sum_t ghat[t][o]*h[t][h]; lane c = h
          int mi = task>>2, o0 = (task&3)*64;
          int m = (mi==3)?5:mi;
          const unsigned short* hb = B + BOFF_H + ((size_t)(b*6+m))*CK*DD;
          const unsigned short* gb = B + BOFF_GB + ((size_t)(b*4+mi))*CK*DD;
          float* w1n = W + OFF_W1N + ((size_t)b*4+mi)*MSZ;
          float hv[64];
          #pragma unroll
          for (int t=0;t<64;t++) hv[t] = bfu(hb[(size_t)t*DD + c]);
          for (int l=tid; l<4096; l+=256){
            int t=l>>6, oo=l&63;
            sT[oo*68+t] = bfu(gb[(size_t)t*DD + o0+oo]) * sEt[t];
          }
          __syncthreads();
          for (int oo=0; oo<64; oo++){
            float s = 0.0f;
            #pragma unroll
            for (int t4=0; t4<16; t4++){
              float4 g4 = *(const float4*)(sT + oo*68 + t4*4);
              s += g4.x*hv[4*t4] + g4.y*hv[4*t4+1] + g4.z*hv[4*t4+2] + g4.w*hv[4*t4+3];
            }
            size_t idx = (size_t)(o0+oo)*DD + c;
            w1n[idx] = ab*w1n[idx] - s;
          }
        } else if (task < 32){
          // W1T[h][o] -= sum_t h[t][h]*ghat[t][o]; lane c = o
          int r = task-16, mi = r>>2, h0 = (r&3)*64;
          int m = (mi==3)?5:mi;
          const unsigned short* hb = B + BOFF_H + ((size_t)(b*6+m))*CK*DD;
          const unsigned short* gb = B + BOFF_GB + ((size_t)(b*4+mi))*CK*DD;
          float* w1t = W + OFF_W1T + ((size_t)b*4+mi)*MSZ;
          float gv[64];
          #pragma unroll
          for (int t=0;t<64;t++) gv[t] = bfu(gb[(size_t)t*DD + c]) * sEt[t];
          for (int l=tid; l<4096; l+=256){
            int t=l>>6, hh=l&63;
            sT[hh*68+t] = bfu(hb[(size_t)t*DD + h0+hh]);
          }
          __syncthreads();
          for (int hh=0; hh<64; hh++){
            float s = 0.0f;
            #pragma unroll
            for (int t4=0; t4<16; t4++){
              float4 h4 = *(const float4*)(sT + hh*68 + t4*4);
              s += h4.x*gv[4*t4] + h4.y*gv[4*t4+1] + h4.z*gv[4*t4+2] + h4.w*gv[4*t4+3];
            }
            size_t idx = (size_t)(h0+hh)*DD + c;
            w1t[idx] = ab*w1t[idx] - s;
          }
        } else if (task < 56){
          // W2T[i][h] -= sum_t khat[t][i]*P[t][h]; lane c = h
          int r = task-32, m = r>>2, i0 = (r&3)*64;
          const unsigned short* pd = B + BOFF_P + ((size_t)(b*6+m))*CK*DD;
          float* w2t = W + OFF_W2T + ((size_t)b*6+m)*MSZ;
          float pv[64];
          #pragma unroll
          for (int t=0;t<64;t++) pv[t] = bfu(pd[(size_t)t*DD + c]);
          for (int l=tid; l<4096; l+=256){
            int t=l>>6, ii=l&63;
            sT[ii*68+t] = bfu(fk[(size_t)t*DD + i0+ii]) * sSk[t];
          }
          __syncthreads();
          for (int ii=0; ii<64; ii++){
            float s = 0.0f;
            #pragma unroll
            for (int t4=0; t4<16; t4++){
              float4 k4 = *(const float4*)(sT + ii*68 + t4*4);
              s += k4.x*pv[4*t4] + k4.y*pv[4*t4+1] + k4.z*pv[4*t4+2] + k4.w*pv[4*t4+3];
            }
            size_t idx = (size_t)(i0+ii)*DD + c;
            w2t[idx] = ab*w2t[idx] - s;
          }
        } else {
          // small-state updates
          int sm = task-56, m = 3+sm;
          const unsigned short* hb = B + BOFF_H + ((size_t)(b*6+m))*CK*DD;
          float s1=0.0f, s2=0.0f;
          #pragma unroll
          for (int t=0;t<64;t++){
            float ge = W[OFF_GS + ((size_t)b*2+sm)*CK + t] * sEt[t];
            s1 += ge * bfu(hb[(size_t)t*DD+c]);
            s2 += ge * bfu(fk[(size_t)t*DD+c]) * sSk[t];
          }
          float* w1s = W + OFF_W1S + ((size_t)b*2+sm)*DD;
          float* wskp= W + OFF_WSK + ((size_t)b*2+sm)*DD;
          w1s[c]  = ab*w1s[c]  - s1;
          wskp[c] = ab*wskp[c] - s2;
        }
        __syncthreads();
      }
    }
    bar += 32; bbar(cnt, bar);
  }
}

// ---------------- host ----------------
extern "C" void kernel_launch(void* const* d_in, const int* in_sizes, int n_in,
                              void* d_out, int out_size, void* d_ws, size_t ws_size,
                              hipStream_t stream){
  const float* x = (const float*)d_in[0];
  float* W = (float*)d_ws;
  __hip_bfloat16* B = (__hip_bfloat16*)(W + FTOT);
  float* out = (float*)d_out;

  initk<<<NB*6, 256, 0, stream>>>(W,
      (const float*)d_in[1], (const float*)d_in[2],
      (const float*)d_in[3], (const float*)d_in[4],
      (const float*)d_in[5], (const float*)d_in[6],
      (const float*)d_in[7], (const float*)d_in[8],
      (const float*)d_in[9], (const float*)d_in[10],
      (const float*)d_in[11], (const float*)d_in[12],
      (const float*)d_in[13], (const float*)d_in[14]);

  pers<<<256, 256, 0, stream>>>(x, W, B, out);
}